// Round 1
// baseline (31.608 us; speedup 1.0000x reference)
//
#include <hip/hip_runtime.h>

// Problem constants (from reference): B=32, S=256, C=50, L=20, F=30, W=3
constexpr int Bc = 32;
constexpr int Sc = 256;
constexpr int Cc = 50;
constexpr int Lc = 20;
constexpr int Fc = 30;
constexpr int Wc = 3;
constexpr int OUT_CH   = Cc * Fc;       // 1500
constexpr int CONV_LEN = Lc - Wc + 1;   // 18
constexpr int XSZ      = Cc * Lc;       // 1000 floats per (b,s)
constexpr int BLOCK    = 256;

__global__ __launch_bounds__(BLOCK)
void charcnn_kernel(const float* __restrict__ x,      // [B*S, C, L]
                    const float* __restrict__ weight, // [C*F, 1, W]
                    const float* __restrict__ bias,   // [C*F]
                    float* __restrict__ out)          // [B*S, C*F]
{
    __shared__ float xs[XSZ];

    const int bs = blockIdx.x;                 // one (b,s) position per block
    const float* xp = x + (size_t)bs * XSZ;

    // Stage the 1000-float slab into LDS, coalesced.
    for (int i = threadIdx.x; i < XSZ; i += BLOCK)
        xs[i] = xp[i];
    __syncthreads();

    float* op = out + (size_t)bs * OUT_CH;

    for (int o = threadIdx.x; o < OUT_CH; o += BLOCK) {
        const int c = o / Fc;                  // group (input channel)
        const float w0 = weight[o * Wc + 0];
        const float w1 = weight[o * Wc + 1];
        const float w2 = weight[o * Wc + 2];

        // Row is 80 B, 16B-aligned -> 5x ds_read_b128 into registers.
        const float4* rowv = (const float4*)(xs + c * Lc);
        float v[Lc];
        #pragma unroll
        for (int i = 0; i < Lc / 4; ++i) {
            const float4 q = rowv[i];
            v[4 * i + 0] = q.x;
            v[4 * i + 1] = q.y;
            v[4 * i + 2] = q.z;
            v[4 * i + 3] = q.w;
        }

        float m = -INFINITY;
        #pragma unroll
        for (int p = 0; p < CONV_LEN; ++p) {
            const float conv = fmaf(v[p], w0, fmaf(v[p + 1], w1, v[p + 2] * w2));
            m = fmaxf(m, conv);
        }
        op[o] = m + bias[o];                   // bias invariant over p: hoisted past max
    }
}

extern "C" void kernel_launch(void* const* d_in, const int* in_sizes, int n_in,
                              void* d_out, int out_size, void* d_ws, size_t ws_size,
                              hipStream_t stream) {
    const float* x      = (const float*)d_in[0];  // [B,S,C,L] fp32
    const float* weight = (const float*)d_in[1];  // [C*F,1,W] fp32
    const float* bias   = (const float*)d_in[2];  // [C*F] fp32
    float* out          = (float*)d_out;          // [B,S,C*F] fp32

    const int nPos = Bc * Sc;                     // 8192 blocks
    charcnn_kernel<<<nPos, BLOCK, 0, stream>>>(x, weight, bias, out);
}

// Round 2
// 29.090 us; speedup vs baseline: 1.0865x; 1.0865x over previous
//
#include <hip/hip_runtime.h>

// Problem constants (from reference): B=32, S=256, C=50, L=20, F=30, W=3
constexpr int Bc = 32;
constexpr int Sc = 256;
constexpr int Cc = 50;
constexpr int Lc = 20;
constexpr int Fc = 30;
constexpr int Wc = 3;
constexpr int OUT_CH   = Cc * Fc;       // 1500
constexpr int CONV_LEN = Lc - Wc + 1;   // 18
constexpr int XSZ      = Cc * Lc;       // 1000 floats per (b,s)
constexpr int BLOCK    = 256;
constexpr int CH_PER_T = 6;             // 6t..6t+5 never crosses a group: 6t%30<=24

__global__ __launch_bounds__(BLOCK, 4)
void charcnn_kernel(const float* __restrict__ x,      // [B*S, C, L]
                    const float* __restrict__ weight, // [C*F, 1, W]
                    const float* __restrict__ bias,   // [C*F]
                    float* __restrict__ out)          // [B*S, C*F]
{
    __shared__ float xs[XSZ];

    const int bs = blockIdx.x;                 // one (b,s) position per block
    const int t  = threadIdx.x;

    // Stage the 4 KB slab into LDS with float4 loads (250 active lanes).
    {
        const float4* src = (const float4*)(x + (size_t)bs * XSZ);
        float4*       dst = (float4*)xs;
        if (t < XSZ / 4) dst[t] = src[t];
    }
    __syncthreads();

    if (t >= OUT_CH / CH_PER_T) return;        // 250 active threads

    // All 6 channels of this thread share one group c = t/5.
    const int c = t / 5;

    // Row: 80 B, 16B-aligned -> 5x ds_read_b128, loaded ONCE per thread.
    float v[Lc];
    {
        const float4* rowv = (const float4*)(xs + c * Lc);
        #pragma unroll
        for (int i = 0; i < Lc / 4; ++i) {
            const float4 q = rowv[i];
            v[4*i+0] = q.x; v[4*i+1] = q.y; v[4*i+2] = q.z; v[4*i+3] = q.w;
        }
    }

    // Weights for channels 6t..6t+5: 18 contiguous floats (8B-aligned) -> 9x float2.
    float w[CH_PER_T * Wc];
    {
        const float2* wp = (const float2*)(weight + t * (CH_PER_T * Wc));
        #pragma unroll
        for (int i = 0; i < (CH_PER_T * Wc) / 2; ++i) {
            const float2 q = wp[i];
            w[2*i] = q.x; w[2*i+1] = q.y;
        }
    }
    // Bias: 6 contiguous floats (8B-aligned) -> 3x float2.
    float bb[CH_PER_T];
    {
        const float2* bp = (const float2*)(bias + t * CH_PER_T);
        #pragma unroll
        for (int i = 0; i < CH_PER_T / 2; ++i) {
            const float2 q = bp[i];
            bb[2*i] = q.x; bb[2*i+1] = q.y;
        }
    }

    float res[CH_PER_T];
    #pragma unroll
    for (int j = 0; j < CH_PER_T; ++j) {
        const float w0 = w[3*j + 0];
        const float w1 = w[3*j + 1];
        const float w2 = w[3*j + 2];

        float cv[CONV_LEN];
        #pragma unroll
        for (int p = 0; p < CONV_LEN; ++p)
            cv[p] = fmaf(v[p], w0, fmaf(v[p+1], w1, v[p+2] * w2));

        // Max reduction via v_max3 fusion: 1 + 7 max3 + 1 fmax = 9 insts.
        float m = fmaxf(fmaxf(cv[0], cv[1]), cv[2]);
        #pragma unroll
        for (int p = 3; p + 1 < CONV_LEN; p += 2)
            m = fmaxf(fmaxf(m, cv[p]), cv[p+1]);
        m = fmaxf(m, cv[CONV_LEN - 1]);

        res[j] = m + bb[j];                    // bias invariant over p: hoisted past max
    }

    // Store 6 floats at out + bs*1500 + 6t (24B-aligned) -> 3x float2, contiguous
    // across lanes (each wave covers a 1536B contiguous span).
    float* op = out + (size_t)bs * OUT_CH + t * CH_PER_T;
    #pragma unroll
    for (int i = 0; i < CH_PER_T / 2; ++i)
        ((float2*)op)[i] = make_float2(res[2*i], res[2*i+1]);
}

extern "C" void kernel_launch(void* const* d_in, const int* in_sizes, int n_in,
                              void* d_out, int out_size, void* d_ws, size_t ws_size,
                              hipStream_t stream) {
    const float* x      = (const float*)d_in[0];  // [B,S,C,L] fp32
    const float* weight = (const float*)d_in[1];  // [C*F,1,W] fp32
    const float* bias   = (const float*)d_in[2];  // [C*F] fp32
    float* out          = (float*)d_out;          // [B,S,C*F] fp32

    const int nPos = Bc * Sc;                     // 8192 blocks
    charcnn_kernel<<<nPos, BLOCK, 0, stream>>>(x, weight, bias, out);
}

// Round 3
// 28.050 us; speedup vs baseline: 1.1268x; 1.0371x over previous
//
#include <hip/hip_runtime.h>

// Problem constants (from reference): B=32, S=256, C=50, L=20, F=30, W=3
constexpr int Bc = 32;
constexpr int Sc = 256;
constexpr int Cc = 50;
constexpr int Lc = 20;
constexpr int Fc = 30;
constexpr int Wc = 3;
constexpr int OUT_CH   = Cc * Fc;       // 1500
constexpr int CONV_LEN = Lc - Wc + 1;   // 18
constexpr int XSZ      = Cc * Lc;       // 1000 floats per (b,s)
constexpr int BLOCK    = 256;
constexpr int CH_PER_T = 6;             // 6t..6t+5 never crosses a group boundary
constexpr int NP       = 4;             // positions per block (weights amortized 4x)

__global__ __launch_bounds__(BLOCK, 4)
void charcnn_kernel(const float* __restrict__ x,      // [B*S, C, L]
                    const float* __restrict__ weight, // [C*F, 1, W]
                    const float* __restrict__ bias,   // [C*F]
                    float* __restrict__ out)          // [B*S, C*F]
{
    __shared__ float xs[2][XSZ];        // double-buffered 4 KB slabs

    const int t    = threadIdx.x;
    const int pos0 = blockIdx.x * NP;

    const bool stager = (t < XSZ / 4);            // 250 lanes stage float4s
    const bool active = (t < OUT_CH / CH_PER_T);  // 250 lanes compute

    // ---- weights/bias once per thread (register-resident across NP positions)
    float w[CH_PER_T * Wc];             // 18 contiguous floats -> 9x float2
    float bb[CH_PER_T];                 // 6 contiguous floats  -> 3x float2
    if (active) {
        const float2* wp = (const float2*)(weight + t * (CH_PER_T * Wc));
        #pragma unroll
        for (int i = 0; i < (CH_PER_T * Wc) / 2; ++i) {
            const float2 q = wp[i];
            w[2*i] = q.x; w[2*i+1] = q.y;
        }
        const float2* bp = (const float2*)(bias + t * CH_PER_T);
        #pragma unroll
        for (int i = 0; i < CH_PER_T / 2; ++i) {
            const float2 q = bp[i];
            bb[2*i] = q.x; bb[2*i+1] = q.y;
        }
    }

    const int c = t / 5;                // group shared by this thread's 6 channels

    // ---- prologue: stage position pos0 into buffer 0
    if (stager)
        ((float4*)xs[0])[t] = ((const float4*)(x + (size_t)pos0 * XSZ))[t];

    for (int p = 0; p < NP; ++p) {
        const int buf = p & 1;

        // T14 async-STAGE split: issue next slab's global load BEFORE compute;
        // its ds_write lands after compute, one barrier per position.
        float4 pre;
        const bool doPre = stager && (p + 1 < NP);
        if (doPre)
            pre = ((const float4*)(x + (size_t)(pos0 + p + 1) * XSZ))[t];

        __syncthreads();                // xs[buf] is ready

        float res[CH_PER_T];
        if (active) {
            // Row: 80 B, 16B-aligned -> 5x ds_read_b128, once per thread.
            float v[Lc];
            const float4* rowv = (const float4*)(xs[buf] + c * Lc);
            #pragma unroll
            for (int i = 0; i < Lc / 4; ++i) {
                const float4 q = rowv[i];
                v[4*i+0] = q.x; v[4*i+1] = q.y; v[4*i+2] = q.z; v[4*i+3] = q.w;
            }

            #pragma unroll
            for (int j = 0; j < CH_PER_T; ++j) {
                const float w0 = w[3*j + 0];
                const float w1 = w[3*j + 1];
                const float w2 = w[3*j + 2];

                float cv[CONV_LEN];
                #pragma unroll
                for (int q = 0; q < CONV_LEN; ++q)
                    cv[q] = fmaf(v[q], w0, fmaf(v[q+1], w1, v[q+2] * w2));

                // Max via v_max3 fusion: 1 fmax-pair + 7 max3 + 1 fmax.
                float m = fmaxf(fmaxf(cv[0], cv[1]), cv[2]);
                #pragma unroll
                for (int q = 3; q + 1 < CONV_LEN; q += 2)
                    m = fmaxf(fmaxf(m, cv[q]), cv[q+1]);
                m = fmaxf(m, cv[CONV_LEN - 1]);

                res[j] = m + bb[j];     // bias invariant over window: hoisted past max
            }
        }

        // Write next slab into the other buffer (separated from its readers by
        // the NEXT iteration's top-of-loop barrier).
        if (doPre)
            ((float4*)xs[buf ^ 1])[t] = pre;

        if (active) {
            // 6 floats at out + (pos0+p)*1500 + 6t: contiguous across lanes.
            float* op = out + (size_t)(pos0 + p) * OUT_CH + t * CH_PER_T;
            #pragma unroll
            for (int i = 0; i < CH_PER_T / 2; ++i)
                ((float2*)op)[i] = make_float2(res[2*i], res[2*i+1]);
        }
    }
}

extern "C" void kernel_launch(void* const* d_in, const int* in_sizes, int n_in,
                              void* d_out, int out_size, void* d_ws, size_t ws_size,
                              hipStream_t stream) {
    const float* x      = (const float*)d_in[0];  // [B,S,C,L] fp32
    const float* weight = (const float*)d_in[1];  // [C*F,1,W] fp32
    const float* bias   = (const float*)d_in[2];  // [C*F] fp32
    float* out          = (float*)d_out;          // [B,S,C*F] fp32

    const int nBlocks = (Bc * Sc) / NP;           // 2048 blocks
    charcnn_kernel<<<nBlocks, BLOCK, 0, stream>>>(x, weight, bias, out);
}